// Round 1
// baseline (1016.323 us; speedup 1.0000x reference)
//
#include <hip/hip_runtime.h>

#define NN 100000
#define NE 3200000
#define FIN 128
#define HD 32
#define CD 8

__device__ __forceinline__ float lrelu(float v) { return v > 0.f ? v : 0.01f * v; }

// p = x @ Wrel^T ; r = x @ Wroot^T + b      (x: [NN,128], W*: [32,128])
__global__ __launch_bounds__(256) void k_proj128(
    const float* __restrict__ x, const float* __restrict__ Wrel,
    const float* __restrict__ Wroot, const float* __restrict__ b,
    float* __restrict__ p, float* __restrict__ r)
{
    __shared__ float Wt[FIN][64];          // Wt[k][j]: j<32 -> Wrel[j][k], j>=32 -> Wroot[j-32][k]
    for (int idx = threadIdx.x; idx < FIN * 64; idx += 256) {
        int k = idx >> 6, j = idx & 63;
        Wt[k][j] = (j < HD) ? Wrel[j * FIN + k] : Wroot[(j - HD) * FIN + k];
    }
    __syncthreads();
    int n = blockIdx.x * 256 + threadIdx.x;
    if (n >= NN) return;

    float accP[HD], accR[HD];
#pragma unroll
    for (int j = 0; j < HD; ++j) { accP[j] = 0.f; accR[j] = 0.f; }

    const float4* x4 = (const float4*)(x + (size_t)n * FIN);
#pragma unroll 2
    for (int k4 = 0; k4 < FIN / 4; ++k4) {
        float4 xv = x4[k4];
        float xs[4] = {xv.x, xv.y, xv.z, xv.w};
#pragma unroll
        for (int kk = 0; kk < 4; ++kk) {
            float xk = xs[kk];
            int k = k4 * 4 + kk;
#pragma unroll
            for (int j = 0; j < HD; ++j) {
                accP[j] += xk * Wt[k][j];
                accR[j] += xk * Wt[k][j + HD];
            }
        }
    }
    float4* pp = (float4*)(p + (size_t)n * HD);
    float4* rr = (float4*)(r + (size_t)n * HD);
#pragma unroll
    for (int q = 0; q < HD / 4; ++q) {
        pp[q] = make_float4(accP[4*q], accP[4*q+1], accP[4*q+2], accP[4*q+3]);
        rr[q] = make_float4(accR[4*q+0] + b[4*q+0], accR[4*q+1] + b[4*q+1],
                            accR[4*q+2] + b[4*q+2], accR[4*q+3] + b[4*q+3]);
    }
}

// agg[dst] += p[src] * ew   over 32 features; thread = (edge, feature)
__global__ __launch_bounds__(256) void k_scatter32(
    const int* __restrict__ src, const int* __restrict__ dst,
    const float* __restrict__ ew, const float* __restrict__ p,
    float* __restrict__ agg)
{
    int gid = blockIdx.x * 256 + threadIdx.x;
    int e = gid >> 5;
    if (e >= NE) return;
    int f = gid & 31;
    int s = src[e], d = dst[e];
    float v = p[(size_t)s * HD + f] * ew[e];
    unsafeAtomicAdd(&agg[(size_t)d * HD + f], v);
}

// h = lrelu(agg + r); p2 = h @ W2rel^T; r2 = h @ W2root^T + b2   (W2*: [32,32])
__global__ __launch_bounds__(256) void k_mid(
    const float* __restrict__ agg, const float* __restrict__ r,
    const float* __restrict__ Wrel, const float* __restrict__ Wroot,
    const float* __restrict__ b,
    float* __restrict__ p2, float* __restrict__ r2)
{
    __shared__ float Ws[HD][64];
    for (int idx = threadIdx.x; idx < HD * 64; idx += 256) {
        int k = idx >> 6, j = idx & 63;
        Ws[k][j] = (j < HD) ? Wrel[j * HD + k] : Wroot[(j - HD) * HD + k];
    }
    __syncthreads();
    int n = blockIdx.x * 256 + threadIdx.x;
    if (n >= NN) return;

    float h[HD];
    const float4* av = (const float4*)(agg + (size_t)n * HD);
    const float4* rv = (const float4*)(r + (size_t)n * HD);
#pragma unroll
    for (int q = 0; q < HD / 4; ++q) {
        float4 a = av[q], rr_ = rv[q];
        h[4*q+0] = lrelu(a.x + rr_.x);
        h[4*q+1] = lrelu(a.y + rr_.y);
        h[4*q+2] = lrelu(a.z + rr_.z);
        h[4*q+3] = lrelu(a.w + rr_.w);
    }
    float accP[HD], accR[HD];
#pragma unroll
    for (int j = 0; j < HD; ++j) { accP[j] = 0.f; accR[j] = 0.f; }
#pragma unroll 4
    for (int k = 0; k < HD; ++k) {
        float hk = h[k];
#pragma unroll
        for (int j = 0; j < HD; ++j) {
            accP[j] += hk * Ws[k][j];
            accR[j] += hk * Ws[k][j + HD];
        }
    }
    float4* pp = (float4*)(p2 + (size_t)n * HD);
    float4* rr2 = (float4*)(r2 + (size_t)n * HD);
#pragma unroll
    for (int q = 0; q < HD / 4; ++q) {
        pp[q] = make_float4(accP[4*q], accP[4*q+1], accP[4*q+2], accP[4*q+3]);
        rr2[q] = make_float4(accR[4*q+0] + b[4*q+0], accR[4*q+1] + b[4*q+1],
                             accR[4*q+2] + b[4*q+2], accR[4*q+3] + b[4*q+3]);
    }
}

// h2 = lrelu(agg2 + r2); p3 = h2 @ W3rel^T; out = h2 @ W3root^T + b3  (W3*: [8,32])
__global__ __launch_bounds__(256) void k_last(
    const float* __restrict__ agg, const float* __restrict__ r,
    const float* __restrict__ Wrel, const float* __restrict__ Wroot,
    const float* __restrict__ b,
    float* __restrict__ p3, float* __restrict__ out)
{
    __shared__ float Ws[HD][16];           // j<8 -> W3rel, j>=8 -> W3root
    for (int idx = threadIdx.x; idx < HD * 16; idx += 256) {
        int k = idx >> 4, j = idx & 15;
        Ws[k][j] = (j < CD) ? Wrel[j * HD + k] : Wroot[(j - CD) * HD + k];
    }
    __syncthreads();
    int n = blockIdx.x * 256 + threadIdx.x;
    if (n >= NN) return;

    float h[HD];
    const float4* av = (const float4*)(agg + (size_t)n * HD);
    const float4* rv = (const float4*)(r + (size_t)n * HD);
#pragma unroll
    for (int q = 0; q < HD / 4; ++q) {
        float4 a = av[q], rr_ = rv[q];
        h[4*q+0] = lrelu(a.x + rr_.x);
        h[4*q+1] = lrelu(a.y + rr_.y);
        h[4*q+2] = lrelu(a.z + rr_.z);
        h[4*q+3] = lrelu(a.w + rr_.w);
    }
    float accP[CD], accR[CD];
#pragma unroll
    for (int j = 0; j < CD; ++j) { accP[j] = 0.f; accR[j] = 0.f; }
#pragma unroll
    for (int k = 0; k < HD; ++k) {
        float hk = h[k];
#pragma unroll
        for (int j = 0; j < CD; ++j) {
            accP[j] += hk * Ws[k][j];
            accR[j] += hk * Ws[k][j + CD];
        }
    }
    float4* pp = (float4*)(p3 + (size_t)n * CD);
    float4* oo = (float4*)(out + (size_t)n * CD);
    pp[0] = make_float4(accP[0], accP[1], accP[2], accP[3]);
    pp[1] = make_float4(accP[4], accP[5], accP[6], accP[7]);
    oo[0] = make_float4(accR[0] + b[0], accR[1] + b[1], accR[2] + b[2], accR[3] + b[3]);
    oo[1] = make_float4(accR[4] + b[4], accR[5] + b[5], accR[6] + b[6], accR[7] + b[7]);
}

// out[dst] += p3[src] * ew   over 8 features; thread = (edge, feature)
__global__ __launch_bounds__(256) void k_scatter8(
    const int* __restrict__ src, const int* __restrict__ dst,
    const float* __restrict__ ew, const float* __restrict__ p,
    float* __restrict__ out)
{
    int gid = blockIdx.x * 256 + threadIdx.x;
    int e = gid >> 3;
    if (e >= NE) return;
    int f = gid & 7;
    int s = src[e], d = dst[e];
    float v = p[(size_t)s * CD + f] * ew[e];
    unsafeAtomicAdd(&out[(size_t)d * CD + f], v);
}

extern "C" void kernel_launch(void* const* d_in, const int* in_sizes, int n_in,
                              void* d_out, int out_size, void* d_ws, size_t ws_size,
                              hipStream_t stream)
{
    const float* x      = (const float*)d_in[0];
    const int*   ei     = (const int*)d_in[1];
    const float* ew     = (const float*)d_in[2];
    const float* W1rel  = (const float*)d_in[3];
    const float* b1     = (const float*)d_in[4];
    const float* W1root = (const float*)d_in[5];
    const float* W2rel  = (const float*)d_in[6];
    const float* b2     = (const float*)d_in[7];
    const float* W2root = (const float*)d_in[8];
    const float* W3rel  = (const float*)d_in[9];
    const float* b3     = (const float*)d_in[10];
    const float* W3root = (const float*)d_in[11];
    float* out = (float*)d_out;

    const int* src = ei;            // edge_index[0]
    const int* dst = ei + NE;       // edge_index[1]

    float* ws   = (float*)d_ws;
    float* p1   = ws;                          // NN*32
    float* r1   = p1   + (size_t)NN * HD;      // NN*32
    float* agg1 = r1   + (size_t)NN * HD;      // NN*32
    float* p2   = agg1 + (size_t)NN * HD;      // NN*32
    float* r2   = p2   + (size_t)NN * HD;      // NN*32
    float* agg2 = r2   + (size_t)NN * HD;      // NN*32
    float* p3   = agg2 + (size_t)NN * HD;      // NN*8
    // total: 20.0M floats = 80 MB of d_ws

    hipMemsetAsync(agg1, 0, (size_t)NN * HD * sizeof(float), stream);
    hipMemsetAsync(agg2, 0, (size_t)NN * HD * sizeof(float), stream);

    const int nodeBlocks = (NN + 255) / 256;
    k_proj128<<<nodeBlocks, 256, 0, stream>>>(x, W1rel, W1root, b1, p1, r1);
    k_scatter32<<<(NE * 32) / 256, 256, 0, stream>>>(src, dst, ew, p1, agg1);
    k_mid<<<nodeBlocks, 256, 0, stream>>>(agg1, r1, W2rel, W2root, b2, p2, r2);
    k_scatter32<<<(NE * 32) / 256, 256, 0, stream>>>(src, dst, ew, p2, agg2);
    k_last<<<nodeBlocks, 256, 0, stream>>>(agg2, r2, W3rel, W3root, b3, p3, out);
    k_scatter8<<<(NE * 8) / 256, 256, 0, stream>>>(src, dst, ew, p3, out);
}

// Round 2
// 772.240 us; speedup vs baseline: 1.3161x; 1.3161x over previous
//
#include <hip/hip_runtime.h>

#define NN 100000
#define NE 3200000
#define FIN 128
#define HD 32
#define CD 8
#define SCAN_CHUNK 1024
#define NB_SCAN ((NN + SCAN_CHUNK - 1) / SCAN_CHUNK)   // 98

__device__ __forceinline__ float lrelu(float v) { return v > 0.f ? v : 0.01f * v; }

// ---------------- dense node kernels ----------------

// p = x @ Wrel^T ; r = x @ Wroot^T + b      (x: [NN,128], W*: [32,128])
__global__ __launch_bounds__(256) void k_proj128(
    const float* __restrict__ x, const float* __restrict__ Wrel,
    const float* __restrict__ Wroot, const float* __restrict__ b,
    float* __restrict__ p, float* __restrict__ r)
{
    __shared__ float Wt[FIN][64];
    for (int idx = threadIdx.x; idx < FIN * 64; idx += 256) {
        int k = idx >> 6, j = idx & 63;
        Wt[k][j] = (j < HD) ? Wrel[j * FIN + k] : Wroot[(j - HD) * FIN + k];
    }
    __syncthreads();
    int n = blockIdx.x * 256 + threadIdx.x;
    if (n >= NN) return;

    float accP[HD], accR[HD];
#pragma unroll
    for (int j = 0; j < HD; ++j) { accP[j] = 0.f; accR[j] = 0.f; }

    const float4* x4 = (const float4*)(x + (size_t)n * FIN);
#pragma unroll 2
    for (int k4 = 0; k4 < FIN / 4; ++k4) {
        float4 xv = x4[k4];
        float xs[4] = {xv.x, xv.y, xv.z, xv.w};
#pragma unroll
        for (int kk = 0; kk < 4; ++kk) {
            float xk = xs[kk];
            int k = k4 * 4 + kk;
#pragma unroll
            for (int j = 0; j < HD; ++j) {
                accP[j] += xk * Wt[k][j];
                accR[j] += xk * Wt[k][j + HD];
            }
        }
    }
    float4* pp = (float4*)(p + (size_t)n * HD);
    float4* rr = (float4*)(r + (size_t)n * HD);
#pragma unroll
    for (int q = 0; q < HD / 4; ++q) {
        pp[q] = make_float4(accP[4*q], accP[4*q+1], accP[4*q+2], accP[4*q+3]);
        rr[q] = make_float4(accR[4*q+0] + b[4*q+0], accR[4*q+1] + b[4*q+1],
                            accR[4*q+2] + b[4*q+2], accR[4*q+3] + b[4*q+3]);
    }
}

// h = lrelu(agg + r); p2 = h @ W2rel^T; r2 = h @ W2root^T + b2   (W2*: [32,32])
// NOTE: p2 aliases agg and r2 aliases r (in-place row update) -> NO __restrict__.
__global__ __launch_bounds__(256) void k_mid(
    const float* agg, const float* r,
    const float* __restrict__ Wrel, const float* __restrict__ Wroot,
    const float* __restrict__ b,
    float* p2, float* r2)
{
    __shared__ float Ws[HD][64];
    for (int idx = threadIdx.x; idx < HD * 64; idx += 256) {
        int k = idx >> 6, j = idx & 63;
        Ws[k][j] = (j < HD) ? Wrel[j * HD + k] : Wroot[(j - HD) * HD + k];
    }
    __syncthreads();
    int n = blockIdx.x * 256 + threadIdx.x;
    if (n >= NN) return;

    float h[HD];
    const float4* av = (const float4*)(agg + (size_t)n * HD);
    const float4* rv = (const float4*)(r + (size_t)n * HD);
#pragma unroll
    for (int q = 0; q < HD / 4; ++q) {
        float4 a = av[q], rr_ = rv[q];
        h[4*q+0] = lrelu(a.x + rr_.x);
        h[4*q+1] = lrelu(a.y + rr_.y);
        h[4*q+2] = lrelu(a.z + rr_.z);
        h[4*q+3] = lrelu(a.w + rr_.w);
    }
    float accP[HD], accR[HD];
#pragma unroll
    for (int j = 0; j < HD; ++j) { accP[j] = 0.f; accR[j] = 0.f; }
#pragma unroll 4
    for (int k = 0; k < HD; ++k) {
        float hk = h[k];
#pragma unroll
        for (int j = 0; j < HD; ++j) {
            accP[j] += hk * Ws[k][j];
            accR[j] += hk * Ws[k][j + HD];
        }
    }
    float4* pp = (float4*)(p2 + (size_t)n * HD);
    float4* rr2 = (float4*)(r2 + (size_t)n * HD);
#pragma unroll
    for (int q = 0; q < HD / 4; ++q) {
        pp[q] = make_float4(accP[4*q], accP[4*q+1], accP[4*q+2], accP[4*q+3]);
        rr2[q] = make_float4(accR[4*q+0] + b[4*q+0], accR[4*q+1] + b[4*q+1],
                             accR[4*q+2] + b[4*q+2], accR[4*q+3] + b[4*q+3]);
    }
}

// h2 = lrelu(agg2 + r2); p3 = h2 @ W3rel^T; out = h2 @ W3root^T + b3  (W3*: [8,32])
__global__ __launch_bounds__(256) void k_last(
    const float* __restrict__ agg, const float* __restrict__ r,
    const float* __restrict__ Wrel, const float* __restrict__ Wroot,
    const float* __restrict__ b,
    float* __restrict__ p3, float* __restrict__ out)
{
    __shared__ float Ws[HD][16];
    for (int idx = threadIdx.x; idx < HD * 16; idx += 256) {
        int k = idx >> 4, j = idx & 15;
        Ws[k][j] = (j < CD) ? Wrel[j * HD + k] : Wroot[(j - CD) * HD + k];
    }
    __syncthreads();
    int n = blockIdx.x * 256 + threadIdx.x;
    if (n >= NN) return;

    float h[HD];
    const float4* av = (const float4*)(agg + (size_t)n * HD);
    const float4* rv = (const float4*)(r + (size_t)n * HD);
#pragma unroll
    for (int q = 0; q < HD / 4; ++q) {
        float4 a = av[q], rr_ = rv[q];
        h[4*q+0] = lrelu(a.x + rr_.x);
        h[4*q+1] = lrelu(a.y + rr_.y);
        h[4*q+2] = lrelu(a.z + rr_.z);
        h[4*q+3] = lrelu(a.w + rr_.w);
    }
    float accP[CD], accR[CD];
#pragma unroll
    for (int j = 0; j < CD; ++j) { accP[j] = 0.f; accR[j] = 0.f; }
#pragma unroll
    for (int k = 0; k < HD; ++k) {
        float hk = h[k];
#pragma unroll
        for (int j = 0; j < CD; ++j) {
            accP[j] += hk * Ws[k][j];
            accR[j] += hk * Ws[k][j + CD];
        }
    }
    float4* pp = (float4*)(p3 + (size_t)n * CD);
    float4* oo = (float4*)(out + (size_t)n * CD);
    pp[0] = make_float4(accP[0], accP[1], accP[2], accP[3]);
    pp[1] = make_float4(accP[4], accP[5], accP[6], accP[7]);
    oo[0] = make_float4(accR[0] + b[0], accR[1] + b[1], accR[2] + b[2], accR[3] + b[3]);
    oo[1] = make_float4(accR[4] + b[4], accR[5] + b[5], accR[6] + b[6], accR[7] + b[7]);
}

// ---------------- CSR build ----------------

__global__ __launch_bounds__(256) void k_hist(const int* __restrict__ dst, int* __restrict__ deg)
{
    int e = blockIdx.x * 256 + threadIdx.x;
    if (e < NE) atomicAdd(&deg[dst[e]], 1);
}

// per-chunk exclusive scan (chunk=1024, 256 thr x 4 elem), chunk totals out
__global__ __launch_bounds__(256) void k_blockscan(
    const int* __restrict__ deg, int* __restrict__ rowstart, int* __restrict__ blockSums)
{
    __shared__ int ts[256];
    int base = blockIdx.x * SCAN_CHUNK;
    int t = threadIdx.x;
    int v[4]; int sum = 0;
#pragma unroll
    for (int i = 0; i < 4; ++i) {
        int idx = base + t * 4 + i;
        v[i] = (idx < NN) ? deg[idx] : 0;
        sum += v[i];
    }
    ts[t] = sum;
    __syncthreads();
    for (int off = 1; off < 256; off <<= 1) {
        int add = (t >= off) ? ts[t - off] : 0;
        __syncthreads();
        ts[t] += add;
        __syncthreads();
    }
    int run = (t == 0) ? 0 : ts[t - 1];
#pragma unroll
    for (int i = 0; i < 4; ++i) {
        int idx = base + t * 4 + i;
        if (idx < NN) rowstart[idx] = run;
        run += v[i];
    }
    if (t == 255) blockSums[blockIdx.x] = ts[255];
}

// scan the 98 chunk totals (one block)
__global__ __launch_bounds__(128) void k_scansums(int* __restrict__ blockSums)
{
    __shared__ int s[128];
    int t = threadIdx.x;
    s[t] = (t < NB_SCAN) ? blockSums[t] : 0;
    __syncthreads();
    for (int off = 1; off < 128; off <<= 1) {
        int add = (t >= off) ? s[t - off] : 0;
        __syncthreads();
        s[t] += add;
        __syncthreads();
    }
    if (t < NB_SCAN) blockSums[t] = (t == 0) ? 0 : s[t - 1];
}

__global__ __launch_bounds__(256) void k_addoff(
    int* __restrict__ rowstart, int* __restrict__ cursor, const int* __restrict__ blockSums)
{
    int i = blockIdx.x * 256 + threadIdx.x;
    if (i < NN) {
        int v = rowstart[i] + blockSums[i >> 10];
        rowstart[i] = v;
        cursor[i] = v;
    }
    if (i == 0) rowstart[NN] = NE;
}

__global__ __launch_bounds__(256) void k_place(
    const int* __restrict__ src, const int* __restrict__ dst, const float* __restrict__ ew,
    int* __restrict__ cursor, int2* __restrict__ epack)
{
    int e = blockIdx.x * 256 + threadIdx.x;
    if (e >= NE) return;
    int d = dst[e];
    int pos = atomicAdd(&cursor[d], 1);
    epack[pos] = make_int2(src[e], __float_as_int(ew[e]));
}

// ---------------- gather aggregation (no atomics) ----------------

// wave per node; lane = (q in 0..1) * 32 + f; 2 edges per iter, unrolled x2
__global__ __launch_bounds__(256) void k_gather32(
    const int* __restrict__ rowstart, const int2* __restrict__ epack,
    const float* __restrict__ p, float* __restrict__ agg)
{
    int wid = (blockIdx.x * 256 + threadIdx.x) >> 6;
    if (wid >= NN) return;
    int lane = threadIdx.x & 63;
    int q = lane >> 5, f = lane & 31;
    int rs = rowstart[wid], re = rowstart[wid + 1];

    float acc0 = 0.f, acc1 = 0.f;
    int e = rs + q;
    for (; e + 2 < re; e += 4) {
        int2 pk0 = epack[e];
        int2 pk1 = epack[e + 2];
        acc0 += p[(size_t)pk0.x * HD + f] * __int_as_float(pk0.y);
        acc1 += p[(size_t)pk1.x * HD + f] * __int_as_float(pk1.y);
    }
    for (; e < re; e += 2) {
        int2 pk = epack[e];
        acc0 += p[(size_t)pk.x * HD + f] * __int_as_float(pk.y);
    }
    float acc = acc0 + acc1;
    acc += __shfl_down(acc, 32);
    if (q == 0) agg[(size_t)wid * HD + f] = acc;
}

// wave per node; lane = (q in 0..7) * 8 + f; 8 edges per iter; adds into out
__global__ __launch_bounds__(256) void k_gather8(
    const int* __restrict__ rowstart, const int2* __restrict__ epack,
    const float* __restrict__ p, float* __restrict__ out)
{
    int wid = (blockIdx.x * 256 + threadIdx.x) >> 6;
    if (wid >= NN) return;
    int lane = threadIdx.x & 63;
    int q = lane >> 3, f = lane & 7;
    int rs = rowstart[wid], re = rowstart[wid + 1];

    float acc = 0.f;
    for (int e = rs + q; e < re; e += 8) {
        int2 pk = epack[e];
        acc += p[(size_t)pk.x * CD + f] * __int_as_float(pk.y);
    }
    acc += __shfl_down(acc, 32);
    acc += __shfl_down(acc, 16);
    acc += __shfl_down(acc, 8);
    if (lane < 8) out[(size_t)wid * CD + f] += acc;
}

// ---------------- launch ----------------

extern "C" void kernel_launch(void* const* d_in, const int* in_sizes, int n_in,
                              void* d_out, int out_size, void* d_ws, size_t ws_size,
                              hipStream_t stream)
{
    const float* x      = (const float*)d_in[0];
    const int*   ei     = (const int*)d_in[1];
    const float* ew     = (const float*)d_in[2];
    const float* W1rel  = (const float*)d_in[3];
    const float* b1     = (const float*)d_in[4];
    const float* W1root = (const float*)d_in[5];
    const float* W2rel  = (const float*)d_in[6];
    const float* b2     = (const float*)d_in[7];
    const float* W2root = (const float*)d_in[8];
    const float* W3rel  = (const float*)d_in[9];
    const float* b3     = (const float*)d_in[10];
    const float* W3root = (const float*)d_in[11];
    float* out = (float*)d_out;

    const int* src = ei;
    const int* dst = ei + NE;

    // workspace layout (epack first for 8B alignment): ~68 MB total
    char* ws = (char*)d_ws;
    int2*  epack    = (int2*)ws;                                  ws += (size_t)NE * sizeof(int2);   // 25.6 MB
    float* P        = (float*)ws;                                 ws += (size_t)NN * HD * 4;         // p1 / agg2
    float* R        = (float*)ws;                                 ws += (size_t)NN * HD * 4;         // r1 / r2 (in-place)
    float* G        = (float*)ws;                                 ws += (size_t)NN * HD * 4;         // agg1 / p2 (in-place)
    float* p3       = (float*)ws;                                 ws += (size_t)NN * CD * 4;         // 3.2 MB
    int*   rowstart = (int*)ws;                                   ws += (size_t)(NN + 1) * 4;
    int*   cursor   = (int*)ws;                                   ws += (size_t)NN * 4;
    int*   blockSums= (int*)ws;

    const int nodeBlocks = (NN + 255) / 256;
    const int edgeBlocks = (NE + 255) / 256;
    const int waveBlocks = (NN + 3) / 4;          // 4 waves (nodes) per 256-thr block

    // --- CSR build (deg lives in cursor) ---
    hipMemsetAsync(cursor, 0, (size_t)NN * 4, stream);
    k_hist<<<edgeBlocks, 256, 0, stream>>>(dst, cursor);
    k_blockscan<<<NB_SCAN, 256, 0, stream>>>(cursor, rowstart, blockSums);
    k_scansums<<<1, 128, 0, stream>>>(blockSums);
    k_addoff<<<nodeBlocks, 256, 0, stream>>>(rowstart, cursor, blockSums);
    k_place<<<edgeBlocks, 256, 0, stream>>>(src, dst, ew, cursor, epack);

    // --- layer 1 ---
    k_proj128<<<nodeBlocks, 256, 0, stream>>>(x, W1rel, W1root, b1, P, R);
    k_gather32<<<waveBlocks, 256, 0, stream>>>(rowstart, epack, P, G);        // G = agg1
    // --- layer 2 ---
    k_mid<<<nodeBlocks, 256, 0, stream>>>(G, R, W2rel, W2root, b2, G, R);     // in-place: G=p2, R=r2
    k_gather32<<<waveBlocks, 256, 0, stream>>>(rowstart, epack, G, P);        // P = agg2
    // --- layer 3 ---
    k_last<<<nodeBlocks, 256, 0, stream>>>(P, R, W3rel, W3root, b3, p3, out);
    k_gather8<<<waveBlocks, 256, 0, stream>>>(rowstart, epack, p3, out);
}

// Round 3
// 569.250 us; speedup vs baseline: 1.7854x; 1.3566x over previous
//
#include <hip/hip_runtime.h>

#define NN 100000
#define NE 3200000
#define FIN 128
#define HD 32
#define CD 8

#define NPB 256                      // nodes per bucket (dst >> 8)
#define NBUCK ((NN + NPB - 1) / NPB) // 391
#define CHUNK_B 8192                 // edges per k_bscatter block

__device__ __forceinline__ float lrelu(float v) { return v > 0.f ? v : 0.01f * v; }

// ---------------- dense node kernels ----------------

// p = x @ Wrel^T ; r = x @ Wroot^T + b      (x: [NN,128], W*: [32,128])
__global__ __launch_bounds__(256) void k_proj128(
    const float* __restrict__ x, const float* __restrict__ Wrel,
    const float* __restrict__ Wroot, const float* __restrict__ b,
    float* __restrict__ p, float* __restrict__ r)
{
    __shared__ float Wt[FIN][64];
    for (int idx = threadIdx.x; idx < FIN * 64; idx += 256) {
        int k = idx >> 6, j = idx & 63;
        Wt[k][j] = (j < HD) ? Wrel[j * FIN + k] : Wroot[(j - HD) * FIN + k];
    }
    __syncthreads();
    int n = blockIdx.x * 256 + threadIdx.x;
    if (n >= NN) return;

    float accP[HD], accR[HD];
#pragma unroll
    for (int j = 0; j < HD; ++j) { accP[j] = 0.f; accR[j] = 0.f; }

    const float4* x4 = (const float4*)(x + (size_t)n * FIN);
#pragma unroll 2
    for (int k4 = 0; k4 < FIN / 4; ++k4) {
        float4 xv = x4[k4];
        float xs[4] = {xv.x, xv.y, xv.z, xv.w};
#pragma unroll
        for (int kk = 0; kk < 4; ++kk) {
            float xk = xs[kk];
            int k = k4 * 4 + kk;
#pragma unroll
            for (int j = 0; j < HD; ++j) {
                accP[j] += xk * Wt[k][j];
                accR[j] += xk * Wt[k][j + HD];
            }
        }
    }
    float4* pp = (float4*)(p + (size_t)n * HD);
    float4* rr = (float4*)(r + (size_t)n * HD);
#pragma unroll
    for (int q = 0; q < HD / 4; ++q) {
        pp[q] = make_float4(accP[4*q], accP[4*q+1], accP[4*q+2], accP[4*q+3]);
        rr[q] = make_float4(accR[4*q+0] + b[4*q+0], accR[4*q+1] + b[4*q+1],
                            accR[4*q+2] + b[4*q+2], accR[4*q+3] + b[4*q+3]);
    }
}

// h = lrelu(agg + r); p2 = h @ W2rel^T; r2 = h @ W2root^T + b2   (W2*: [32,32])
// p2 aliases agg, r2 aliases r -> NO __restrict__.
__global__ __launch_bounds__(256) void k_mid(
    const float* agg, const float* r,
    const float* __restrict__ Wrel, const float* __restrict__ Wroot,
    const float* __restrict__ b,
    float* p2, float* r2)
{
    __shared__ float Ws[HD][64];
    for (int idx = threadIdx.x; idx < HD * 64; idx += 256) {
        int k = idx >> 6, j = idx & 63;
        Ws[k][j] = (j < HD) ? Wrel[j * HD + k] : Wroot[(j - HD) * HD + k];
    }
    __syncthreads();
    int n = blockIdx.x * 256 + threadIdx.x;
    if (n >= NN) return;

    float h[HD];
    const float4* av = (const float4*)(agg + (size_t)n * HD);
    const float4* rv = (const float4*)(r + (size_t)n * HD);
#pragma unroll
    for (int q = 0; q < HD / 4; ++q) {
        float4 a = av[q], rr_ = rv[q];
        h[4*q+0] = lrelu(a.x + rr_.x);
        h[4*q+1] = lrelu(a.y + rr_.y);
        h[4*q+2] = lrelu(a.z + rr_.z);
        h[4*q+3] = lrelu(a.w + rr_.w);
    }
    float accP[HD], accR[HD];
#pragma unroll
    for (int j = 0; j < HD; ++j) { accP[j] = 0.f; accR[j] = 0.f; }
#pragma unroll 4
    for (int k = 0; k < HD; ++k) {
        float hk = h[k];
#pragma unroll
        for (int j = 0; j < HD; ++j) {
            accP[j] += hk * Ws[k][j];
            accR[j] += hk * Ws[k][j + HD];
        }
    }
    float4* pp = (float4*)(p2 + (size_t)n * HD);
    float4* rr2 = (float4*)(r2 + (size_t)n * HD);
#pragma unroll
    for (int q = 0; q < HD / 4; ++q) {
        pp[q] = make_float4(accP[4*q], accP[4*q+1], accP[4*q+2], accP[4*q+3]);
        rr2[q] = make_float4(accR[4*q+0] + b[4*q+0], accR[4*q+1] + b[4*q+1],
                             accR[4*q+2] + b[4*q+2], accR[4*q+3] + b[4*q+3]);
    }
}

// h2 = lrelu(agg2 + r2); p3 = h2 @ W3rel^T; out = h2 @ W3root^T + b3  (W3*: [8,32])
__global__ __launch_bounds__(256) void k_last(
    const float* __restrict__ agg, const float* __restrict__ r,
    const float* __restrict__ Wrel, const float* __restrict__ Wroot,
    const float* __restrict__ b,
    float* __restrict__ p3, float* __restrict__ out)
{
    __shared__ float Ws[HD][16];
    for (int idx = threadIdx.x; idx < HD * 16; idx += 256) {
        int k = idx >> 4, j = idx & 15;
        Ws[k][j] = (j < CD) ? Wrel[j * HD + k] : Wroot[(j - CD) * HD + k];
    }
    __syncthreads();
    int n = blockIdx.x * 256 + threadIdx.x;
    if (n >= NN) return;

    float h[HD];
    const float4* av = (const float4*)(agg + (size_t)n * HD);
    const float4* rv = (const float4*)(r + (size_t)n * HD);
#pragma unroll
    for (int q = 0; q < HD / 4; ++q) {
        float4 a = av[q], rr_ = rv[q];
        h[4*q+0] = lrelu(a.x + rr_.x);
        h[4*q+1] = lrelu(a.y + rr_.y);
        h[4*q+2] = lrelu(a.z + rr_.z);
        h[4*q+3] = lrelu(a.w + rr_.w);
    }
    float accP[CD], accR[CD];
#pragma unroll
    for (int j = 0; j < CD; ++j) { accP[j] = 0.f; accR[j] = 0.f; }
#pragma unroll
    for (int k = 0; k < HD; ++k) {
        float hk = h[k];
#pragma unroll
        for (int j = 0; j < CD; ++j) {
            accP[j] += hk * Ws[k][j];
            accR[j] += hk * Ws[k][j + CD];
        }
    }
    float4* pp = (float4*)(p3 + (size_t)n * CD);
    float4* oo = (float4*)(out + (size_t)n * CD);
    pp[0] = make_float4(accP[0], accP[1], accP[2], accP[3]);
    pp[1] = make_float4(accP[4], accP[5], accP[6], accP[7]);
    oo[0] = make_float4(accR[0] + b[0], accR[1] + b[1], accR[2] + b[2], accR[3] + b[3]);
    oo[1] = make_float4(accR[4] + b[4], accR[5] + b[5], accR[6] + b[6], accR[7] + b[7]);
}

// ---------------- bucketed CSR build ----------------
// bucket b = dst >> 8 (256 nodes/bucket). All scatters stay within
// ~68 KB bucket spans -> L2 write-combining instead of 64B/edge blowout.

// per-block LDS bucket histogram -> global bucket counts
__global__ __launch_bounds__(256) void k_bhist(
    const int* __restrict__ dst, int* __restrict__ bcnt)
{
    __shared__ int lc[NBUCK];
    int t = threadIdx.x;
    for (int i = t; i < NBUCK; i += 256) lc[i] = 0;
    __syncthreads();
    for (int e = blockIdx.x * 256 + t; e < NE; e += gridDim.x * 256)
        atomicAdd(&lc[dst[e] >> 8], 1);
    __syncthreads();
    for (int i = t; i < NBUCK; i += 256) {
        int c = lc[i];
        if (c) atomicAdd(&bcnt[i], c);
    }
}

// exclusive scan of 391 bucket counts (one block)
__global__ __launch_bounds__(512) void k_bscan(
    const int* __restrict__ bcnt, int* __restrict__ bbase, int* __restrict__ bcur)
{
    __shared__ int s[512];
    int t = threadIdx.x;
    s[t] = (t < NBUCK) ? bcnt[t] : 0;
    __syncthreads();
    for (int off = 1; off < 512; off <<= 1) {
        int a = (t >= off) ? s[t - off] : 0;
        __syncthreads();
        s[t] += a;
        __syncthreads();
    }
    int excl = t ? s[t - 1] : 0;
    if (t < NBUCK) { bbase[t] = excl; bcur[t] = excl; }
    if (t == 0) bbase[NBUCK] = NE;
}

// scatter edges into bucket-contiguous tmp; block reserves contiguous runs
__global__ __launch_bounds__(256) void k_bscatter(
    const int* __restrict__ src, const int* __restrict__ dst, const float* __restrict__ ew,
    int* __restrict__ bcur, int2* __restrict__ tmp)
{
    __shared__ int lc[NBUCK];
    int t = threadIdx.x;
    for (int i = t; i < NBUCK; i += 256) lc[i] = 0;
    __syncthreads();
    int base = blockIdx.x * CHUNK_B;
#pragma unroll 4
    for (int k = 0; k < CHUNK_B / 256; ++k) {
        int e = base + k * 256 + t;
        if (e < NE) atomicAdd(&lc[dst[e] >> 8], 1);
    }
    __syncthreads();
    for (int b = t; b < NBUCK; b += 256) {
        int c = lc[b];
        lc[b] = c ? atomicAdd(&bcur[b], c) : 0;
    }
    __syncthreads();
#pragma unroll 4
    for (int k = 0; k < CHUNK_B / 256; ++k) {
        int e = base + k * 256 + t;
        if (e < NE) {
            int d = dst[e];
            int pos = atomicAdd(&lc[d >> 8], 1);
            tmp[pos] = make_int2(src[e] | ((d & 255) << 17), __float_as_int(ew[e]));
        }
    }
}

// one block per bucket: per-node hist + scan -> rowstart; in-bucket counting sort
__global__ __launch_bounds__(256) void k_bsort(
    const int* __restrict__ bbase, const int2* __restrict__ tmp,
    int2* __restrict__ epack, int* __restrict__ rowstart)
{
    int b = blockIdx.x, t = threadIdx.x;
    int lo = bbase[b], hi = bbase[b + 1], cnt = hi - lo;
    __shared__ int hist[NPB];
    __shared__ int sc[NPB];
    __shared__ int cur[NPB];
    hist[t] = 0;
    __syncthreads();
    for (int i = t; i < cnt; i += 256)
        atomicAdd(&hist[(tmp[lo + i].x >> 17) & 255], 1);
    __syncthreads();
    sc[t] = hist[t];
    __syncthreads();
    for (int off = 1; off < 256; off <<= 1) {
        int a = (t >= off) ? sc[t - off] : 0;
        __syncthreads();
        sc[t] += a;
        __syncthreads();
    }
    int excl = t ? sc[t - 1] : 0;
    int node = (b << 8) + t;
    if (node < NN) rowstart[node] = lo + excl;
    if (b == 0 && t == 0) rowstart[NN] = NE;
    cur[t] = lo + excl;
    __syncthreads();
    for (int i = t; i < cnt; i += 256) {
        int2 v = tmp[lo + i];
        int l = (v.x >> 17) & 255;
        int pos = atomicAdd(&cur[l], 1);
        epack[pos] = make_int2(v.x & 0x1FFFF, v.y);
    }
}

// ---------------- gather aggregation (no atomics) ----------------

// wave per node; lane = (q in 0..1) * 32 + f
__global__ __launch_bounds__(256) void k_gather32(
    const int* __restrict__ rowstart, const int2* __restrict__ epack,
    const float* __restrict__ p, float* __restrict__ agg)
{
    int wid = (blockIdx.x * 256 + threadIdx.x) >> 6;
    if (wid >= NN) return;
    int lane = threadIdx.x & 63;
    int q = lane >> 5, f = lane & 31;
    int rs = rowstart[wid], re = rowstart[wid + 1];

    float acc0 = 0.f, acc1 = 0.f;
    int e = rs + q;
    for (; e + 2 < re; e += 4) {
        int2 pk0 = epack[e];
        int2 pk1 = epack[e + 2];
        acc0 += p[(size_t)pk0.x * HD + f] * __int_as_float(pk0.y);
        acc1 += p[(size_t)pk1.x * HD + f] * __int_as_float(pk1.y);
    }
    for (; e < re; e += 2) {
        int2 pk = epack[e];
        acc0 += p[(size_t)pk.x * HD + f] * __int_as_float(pk.y);
    }
    float acc = acc0 + acc1;
    acc += __shfl_down(acc, 32);
    if (q == 0) agg[(size_t)wid * HD + f] = acc;
}

// wave per node; lane = (q in 0..7) * 8 + f; adds into out
__global__ __launch_bounds__(256) void k_gather8(
    const int* __restrict__ rowstart, const int2* __restrict__ epack,
    const float* __restrict__ p, float* __restrict__ out)
{
    int wid = (blockIdx.x * 256 + threadIdx.x) >> 6;
    if (wid >= NN) return;
    int lane = threadIdx.x & 63;
    int q = lane >> 3, f = lane & 7;
    int rs = rowstart[wid], re = rowstart[wid + 1];

    float acc = 0.f;
    for (int e = rs + q; e < re; e += 8) {
        int2 pk = epack[e];
        acc += p[(size_t)pk.x * CD + f] * __int_as_float(pk.y);
    }
    acc += __shfl_down(acc, 32);
    acc += __shfl_down(acc, 16);
    acc += __shfl_down(acc, 8);
    if (lane < 8) out[(size_t)wid * CD + f] += acc;
}

// ---------------- launch ----------------

extern "C" void kernel_launch(void* const* d_in, const int* in_sizes, int n_in,
                              void* d_out, int out_size, void* d_ws, size_t ws_size,
                              hipStream_t stream)
{
    const float* x      = (const float*)d_in[0];
    const int*   ei     = (const int*)d_in[1];
    const float* ew     = (const float*)d_in[2];
    const float* W1rel  = (const float*)d_in[3];
    const float* b1     = (const float*)d_in[4];
    const float* W1root = (const float*)d_in[5];
    const float* W2rel  = (const float*)d_in[6];
    const float* b2     = (const float*)d_in[7];
    const float* W2root = (const float*)d_in[8];
    const float* W3rel  = (const float*)d_in[9];
    const float* b3     = (const float*)d_in[10];
    const float* W3root = (const float*)d_in[11];
    float* out = (float*)d_out;

    const int* src = ei;
    const int* dst = ei + NE;

    // workspace (~68 MB). tmp aliases P+R: tmp is dead before k_proj128 writes P,R.
    char* ws = (char*)d_ws;
    int2*  epack    = (int2*)ws;   ws += (size_t)NE * sizeof(int2);      // 25.6 MB
    char*  unionA   = ws;          ws += (size_t)NE * sizeof(int2);      // 25.6 MB
    float* G        = (float*)ws;  ws += (size_t)NN * HD * 4;            // 12.8 MB
    float* p3       = (float*)ws;  ws += (size_t)NN * CD * 4;            // 3.2 MB
    int*   rowstart = (int*)ws;    ws += (size_t)(NN + 1) * 4;
    int*   bcnt     = (int*)ws;    ws += (size_t)NBUCK * 4;
    int*   bbase    = (int*)ws;    ws += (size_t)(NBUCK + 1) * 4;
    int*   bcur     = (int*)ws;

    int2*  tmp = (int2*)unionA;
    float* P   = (float*)unionA;              // p1 / agg2
    float* R   = P + (size_t)NN * HD;         // r1 / r2 (in-place)

    const int nodeBlocks = (NN + 255) / 256;
    const int waveBlocks = (NN + 3) / 4;
    const int scatBlocks = (NE + CHUNK_B - 1) / CHUNK_B;   // 391

    // --- CSR build ---
    hipMemsetAsync(bcnt, 0, (size_t)NBUCK * 4, stream);
    k_bhist<<<512, 256, 0, stream>>>(dst, bcnt);
    k_bscan<<<1, 512, 0, stream>>>(bcnt, bbase, bcur);
    k_bscatter<<<scatBlocks, 256, 0, stream>>>(src, dst, ew, bcur, tmp);
    k_bsort<<<NBUCK, 256, 0, stream>>>(bbase, tmp, epack, rowstart);

    // --- layer 1 ---
    k_proj128<<<nodeBlocks, 256, 0, stream>>>(x, W1rel, W1root, b1, P, R);
    k_gather32<<<waveBlocks, 256, 0, stream>>>(rowstart, epack, P, G);     // G = agg1
    // --- layer 2 ---
    k_mid<<<nodeBlocks, 256, 0, stream>>>(G, R, W2rel, W2root, b2, G, R);  // in-place
    k_gather32<<<waveBlocks, 256, 0, stream>>>(rowstart, epack, G, P);     // P = agg2
    // --- layer 3 ---
    k_last<<<nodeBlocks, 256, 0, stream>>>(P, R, W3rel, W3root, b3, p3, out);
    k_gather8<<<waveBlocks, 256, 0, stream>>>(rowstart, epack, p3, out);
}